// Round 4
// baseline (92.263 us; speedup 1.0000x reference)
//
#include <hip/hip_runtime.h>

// Problem constants: B=8, S=2048, D=512, G=2, V=320, CV=128
#define M_ROWS 16384   // B*S
#define K_DIM  512
#define N_COLS 640     // G*V
#define V_CODES 320
#define CV_DIM 128

typedef _Float16 half8 __attribute__((ext_vector_type(8)));
typedef _Float16 half4v __attribute__((ext_vector_type(4)));
typedef float floatx4 __attribute__((ext_vector_type(4)));

__device__ inline void gll16(const void* g, void* l) {
    __builtin_amdgcn_global_load_lds(
        (const __attribute__((address_space(1))) void*)g,
        (__attribute__((address_space(3))) void*)l, 16, 0, 0);
}

// ---------------------------------------------------------------------------
// Kernel 0: prepW — LDS-tiled transpose W (512,640) f32 -> Wt (640,512) f16;
// block 320 zeroes the global marginal.
// ---------------------------------------------------------------------------
__global__ __launch_bounds__(256)
void prepW(const float* __restrict__ W, _Float16* __restrict__ Wt,
           float* __restrict__ marginal) {
    __shared__ float tile[32][33];
    const int b = blockIdx.x, t = threadIdx.x;
    if (b == 320) {
        for (int i = t; i < 640; i += 256) marginal[i] = 0.f;
        return;
    }
    const int n0 = (b % 20) * 32, k0 = (b / 20) * 32;
    {
        const int kk = t >> 3, nn4 = (t & 7) << 2;
        const float4 w = *(const float4*)(W + (size_t)(k0 + kk) * 640 + n0 + nn4);
        tile[kk][nn4 + 0] = w.x; tile[kk][nn4 + 1] = w.y;
        tile[kk][nn4 + 2] = w.z; tile[kk][nn4 + 3] = w.w;
    }
    __syncthreads();
    {
        const int nn = t >> 3, kk4 = (t & 7) << 2;
        half4v h = {(_Float16)tile[kk4 + 0][nn], (_Float16)tile[kk4 + 1][nn],
                    (_Float16)tile[kk4 + 2][nn], (_Float16)tile[kk4 + 3][nn]};
        *(half4v*)(Wt + (size_t)(n0 + nn) * 512 + k0 + kk4) = h;
    }
}

// ---------------------------------------------------------------------------
// Kernel 1: GEMM logits = A(f32,16384x512) @ Wt^T + bias -> f16
// 128x128 tile, BK=64, 4 waves. A: reg-staged f32->f16 with ^(m&7) XOR-swizzled
// ds_write_b64 (write+read same involution). B: gll16 16B, linear LDS dest,
// pre-swizzled global source (rule #21, round-2-proven).
// ---------------------------------------------------------------------------
__global__ __launch_bounds__(256)
void gemm(const float* __restrict__ A, const _Float16* __restrict__ Bt,
          const float* __restrict__ bias, _Float16* __restrict__ C) {
    __shared__ _Float16 As[128 * 64];   // swizzled [row(128B)][chunk^ (m&7)]
    __shared__ _Float16 Bs[128 * 64];   // same layout, filled by gll16
    const int t = threadIdx.x;
    const int wave = t >> 6, lane = t & 63;
    const int bn = blockIdx.x, bm = blockIdx.y;
    const int wr = wave >> 1, wc = wave & 1;

    floatx4 acc[4][4];
#pragma unroll
    for (int i = 0; i < 4; ++i)
#pragma unroll
        for (int j = 0; j < 4; ++j) acc[i][j] = (floatx4){0.f, 0.f, 0.f, 0.f};

    // B staging map (round 2): 32-row groups, lane-ordered 16B chunks
    const int m_st = t >> 3;            // 0..31
    const int c_st = t & 7;             // chunk within 128B row
    const _Float16* Bbase = Bt + (size_t)(bn * 128) * 512;

    // A staging map: 16-row groups, 16 lanes x 16B f32 contiguous per row
    const int ar = t >> 4;              // 0..15 (row within 16-row group)
    const int ac = t & 15;              // float4 index within 64 k-floats
    const int a_ds_half = (ac & 1) * 8; // 8B half within 16B chunk
    const int a_chunk = ac >> 1;        // data chunk 0..7

    for (int k0 = 0; k0 < 512; k0 += 64) {
#pragma unroll
        for (int r = 0; r < 4; ++r) {
            const int n  = r * 32 + m_st;
            const int lc = c_st ^ (n & 7);
            gll16(Bbase + (size_t)n * 512 + k0 + lc * 8,
                  (char*)Bs + r * 4096 + wave * 1024);
        }
#pragma unroll
        for (int i = 0; i < 8; ++i) {
            const int m = i * 16 + ar;
            const float4 v = *(const float4*)(A + (size_t)(bm * 128 + m) * 512
                                              + k0 + ac * 4);
            half4v h = {(_Float16)v.x, (_Float16)v.y, (_Float16)v.z, (_Float16)v.w};
            *(half4v*)((char*)As + m * 128 + ((a_chunk ^ (m & 7)) << 4) + a_ds_half) = h;
        }
        __syncthreads();

#pragma unroll
        for (int kk = 0; kk < 2; ++kk) {
            half8 af[4], bf[4];
#pragma unroll
            for (int mi = 0; mi < 4; ++mi) {
                const int ra = wr * 64 + mi * 16 + (lane & 15);
                const int j  = kk * 4 + (lane >> 4);
                af[mi] = *(const half8*)((const char*)As +
                           ra * 128 + ((j ^ (ra & 7)) << 4));
            }
#pragma unroll
            for (int ni = 0; ni < 4; ++ni) {
                const int rb = wc * 64 + ni * 16 + (lane & 15);
                const int j  = kk * 4 + (lane >> 4);
                bf[ni] = *(const half8*)((const char*)Bs +
                           rb * 128 + ((j ^ (rb & 7)) << 4));
            }
#pragma unroll
            for (int mi = 0; mi < 4; ++mi)
#pragma unroll
                for (int ni = 0; ni < 4; ++ni)
                    acc[mi][ni] = __builtin_amdgcn_mfma_f32_16x16x32_f16(
                        af[mi], bf[ni], acc[mi][ni], 0, 0, 0);
        }
        __syncthreads();
    }

    const int row0 = bm * 128 + wr * 64;
    const int col0 = bn * 128 + wc * 64;
#pragma unroll
    for (int ni = 0; ni < 4; ++ni) {
        const int col = col0 + ni * 16 + (lane & 15);
        const float bv = bias[col];
#pragma unroll
        for (int mi = 0; mi < 4; ++mi) {
#pragma unroll
            for (int rg = 0; rg < 4; ++rg) {
                const int row = row0 + mi * 16 + (lane >> 4) * 4 + rg;
                C[(size_t)row * 640 + col] = (_Float16)(acc[mi][ni][rg] + bv);
            }
        }
    }
}

// ---------------------------------------------------------------------------
// Kernel 2: rowops — 512 blocks x 1024 threads (16 waves), 4 rows per wave.
// argmax(logits+gumbels) -> codevector gather; noise-free softmax -> marginal
// (register acc -> LDS atomics -> 640 global atomics per block).
// ---------------------------------------------------------------------------
__global__ __launch_bounds__(1024, 8)
void rowops(const _Float16* __restrict__ logits, const float* __restrict__ gum,
            const float* __restrict__ cv, float* __restrict__ out,
            float* __restrict__ marginal) {
    __shared__ float smarg[640];
    const int t = threadIdx.x;
    const int wave = t >> 6, lane = t & 63;
    if (t < 640) smarg[t] = 0.f;
    __syncthreads();

    float mreg[2][5];
#pragma unroll
    for (int g = 0; g < 2; ++g)
#pragma unroll
        for (int j = 0; j < 5; ++j) mreg[g][j] = 0.f;

#pragma unroll
    for (int i = 0; i < 4; ++i) {
        const int r = blockIdx.x * 64 + wave * 4 + i;
        const int g = i & 1;                      // == r & 1 (wave*4 even)
        const _Float16* lrow = logits + (size_t)r * V_CODES;
        const float* grow = gum + (size_t)r * V_CODES;

        float lv[5];
        float bestv = -1e30f;
        int   besti = 0;
        float lmax = -1e30f;
#pragma unroll
        for (int j = 0; j < 5; ++j) {
            const int v = lane + 64 * j;
            const float L = (float)lrow[v];
            const float Nz = L + grow[v];
            lv[j] = L;
            if (Nz > bestv) { bestv = Nz; besti = v; }
            lmax = fmaxf(lmax, L);
        }
#pragma unroll
        for (int off = 32; off; off >>= 1) {
            const float ov = __shfl_down(bestv, off);
            const int   oi = __shfl_down(besti, off);
            if (ov > bestv || (ov == bestv && oi < besti)) { bestv = ov; besti = oi; }
            lmax = fmaxf(lmax, __shfl_down(lmax, off));
        }
        besti = __shfl(besti, 0);
        lmax  = __shfl(lmax, 0);

        float ex[5];
        float sum = 0.f;
#pragma unroll
        for (int j = 0; j < 5; ++j) { ex[j] = __expf(lv[j] - lmax); sum += ex[j]; }
#pragma unroll
        for (int off = 32; off; off >>= 1) sum += __shfl_down(sum, off);
        sum = __shfl(sum, 0);
        const float inv = 1.f / sum;
#pragma unroll
        for (int j = 0; j < 5; ++j) mreg[g][j] += ex[j] * inv;

        const int n = r >> 1;
        const float2 cvv =
            ((const float2*)(cv + ((size_t)g * V_CODES + besti) * CV_DIM))[lane];
        ((float2*)(out + (size_t)n * 256 + g * CV_DIM))[lane] = cvv;
    }

#pragma unroll
    for (int g = 0; g < 2; ++g)
#pragma unroll
        for (int j = 0; j < 5; ++j)
            atomicAdd(&smarg[g * V_CODES + lane + 64 * j], mreg[g][j]);
    __syncthreads();
    if (t < 640) atomicAdd(marginal + t, smarg[t]);
}

// ---------------------------------------------------------------------------
// Kernel 3: finalize perplexity from the global marginal (640 floats).
// ---------------------------------------------------------------------------
__global__ __launch_bounds__(640)
void finalize(const float* __restrict__ marginal, float* __restrict__ perp_out) {
    __shared__ float terms[640];
    __shared__ float gsum[2];
    const int t = threadIdx.x;

    const float m = marginal[t] * (1.0f / (float)M_ROWS);
    terms[t] = -m * __logf(m + 1e-7f);
    __syncthreads();

    if (t < 128) {
        const int g = t >> 6, lane = t & 63;
        float e = 0.f;
#pragma unroll
        for (int j = 0; j < 5; ++j) e += terms[g * V_CODES + lane + 64 * j];
#pragma unroll
        for (int off = 32; off; off >>= 1) e += __shfl_down(e, off);
        if (lane == 0) gsum[g] = e;
    }
    __syncthreads();
    if (t == 0) perp_out[0] = __expf(gsum[0]) + __expf(gsum[1]);
}

// ---------------------------------------------------------------------------
extern "C" void kernel_launch(void* const* d_in, const int* in_sizes, int n_in,
                              void* d_out, int out_size, void* d_ws, size_t ws_size,
                              hipStream_t stream) {
    (void)in_sizes; (void)n_in; (void)out_size; (void)ws_size;
    const float* hs = (const float*)d_in[0];   // (8,2048,512) f32
    const float* W  = (const float*)d_in[1];   // (512,640)    f32
    const float* bi = (const float*)d_in[2];   // (640,)       f32
    const float* cv = (const float*)d_in[3];   // (1,640,128)  f32
    const float* gu = (const float*)d_in[4];   // (32768,320)  f32
    float* out = (float*)d_out;                // 16384*256 + 1

    // ws: logits f16 (21 MB) + Wt f16 (640 KB) + marginal (640 f32)
    _Float16* logitsH = (_Float16*)d_ws;
    _Float16* Wt      = logitsH + (size_t)M_ROWS * N_COLS;
    float*    marginal= (float*)(Wt + (size_t)N_COLS * K_DIM);

    prepW<<<321, 256, 0, stream>>>(W, Wt, marginal);
    gemm<<<dim3(5, 128), 256, 0, stream>>>(hs, Wt, bi, logitsH);
    rowops<<<512, 1024, 0, stream>>>(logitsH, gu, cv, out, marginal);
    finalize<<<1, 640, 0, stream>>>(marginal, out + (size_t)M_ROWS * 256);
}

// Round 5
// 80.791 us; speedup vs baseline: 1.1420x; 1.1420x over previous
//
#include <hip/hip_runtime.h>

// Problem constants: B=8, S=2048, D=512, G=2, V=320, CV=128
#define M_ROWS 16384   // B*S
#define K_DIM  512
#define N_COLS 640     // G*V
#define V_CODES 320
#define CV_DIM 128

typedef _Float16 half8 __attribute__((ext_vector_type(8)));
typedef _Float16 half4v __attribute__((ext_vector_type(4)));
typedef float floatx4 __attribute__((ext_vector_type(4)));

__device__ inline void gll16(const void* g, void* l) {
    __builtin_amdgcn_global_load_lds(
        (const __attribute__((address_space(1))) void*)g,
        (__attribute__((address_space(3))) void*)l, 16, 0, 0);
}

// ---------------------------------------------------------------------------
// Kernel 0: prep — blocks 0..2047: A f32->f16 (vectorized);
// blocks 2048..2367: W (512,640) -> Wt (640,512) f16 via LDS-tiled transpose;
// block 2368: zero marginal.
// ---------------------------------------------------------------------------
__global__ __launch_bounds__(256)
void prep(const float* __restrict__ A, const float* __restrict__ W,
          _Float16* __restrict__ Af, _Float16* __restrict__ Wt,
          float* __restrict__ marginal) {
    __shared__ float tile[32][33];
    const int b = blockIdx.x, t = threadIdx.x;
    if (b < 2048) {
        const float4* A4 = (const float4*)A;
        half4v* O4 = (half4v*)Af;
        const size_t gid = (size_t)b * 256 + t;
#pragma unroll
        for (int it = 0; it < 4; ++it) {
            size_t i = (size_t)it * 524288 + gid;   // 2,097,152 float4 total
            float4 v = A4[i];
            half4v o = {(_Float16)v.x, (_Float16)v.y, (_Float16)v.z, (_Float16)v.w};
            O4[i] = o;
        }
    } else if (b < 2368) {
        const int bb = b - 2048;                    // 0..319
        const int n0 = (bb % 20) * 32, k0 = (bb / 20) * 32;
        {
            const int kk = t >> 3, nn4 = (t & 7) << 2;
            const float4 w = *(const float4*)(W + (size_t)(k0 + kk) * 640 + n0 + nn4);
            tile[kk][nn4 + 0] = w.x; tile[kk][nn4 + 1] = w.y;
            tile[kk][nn4 + 2] = w.z; tile[kk][nn4 + 3] = w.w;
        }
        __syncthreads();
        {
            const int nn = t >> 3, kk4 = (t & 7) << 2;
            half4v h = {(_Float16)tile[kk4 + 0][nn], (_Float16)tile[kk4 + 1][nn],
                        (_Float16)tile[kk4 + 2][nn], (_Float16)tile[kk4 + 3][nn]};
            *(half4v*)(Wt + (size_t)(n0 + nn) * 512 + k0 + kk4) = h;
        }
    } else {
        for (int i = t; i < 640; i += 256) marginal[i] = 0.f;
    }
}

// ---------------------------------------------------------------------------
// Kernel 1: MFMA f16 GEMM (round-2-proven): logits = Af @ Wt^T + bias -> f16
// 128x128 tile, BK=64, 4 waves, gll16 staging, XOR-swizzled source (rule #21).
// ---------------------------------------------------------------------------
__global__ __launch_bounds__(256)
void gemm(const _Float16* __restrict__ A, const _Float16* __restrict__ Bt,
          const float* __restrict__ bias, _Float16* __restrict__ C) {
    __shared__ _Float16 As[128 * 64];
    __shared__ _Float16 Bs[128 * 64];
    const int t = threadIdx.x;
    const int wave = t >> 6, lane = t & 63;
    const int bn = blockIdx.x, bm = blockIdx.y;
    const int wr = wave >> 1, wc = wave & 1;

    floatx4 acc[4][4];
#pragma unroll
    for (int i = 0; i < 4; ++i)
#pragma unroll
        for (int j = 0; j < 4; ++j) acc[i][j] = (floatx4){0.f, 0.f, 0.f, 0.f};

    const int m_st = t >> 3;     // 0..31
    const int c_st = t & 7;      // 16B chunk within 128B row

    const _Float16* Abase = A  + (size_t)(bm * 128) * 512;
    const _Float16* Bbase = Bt + (size_t)(bn * 128) * 512;

    for (int k0 = 0; k0 < 512; k0 += 64) {
#pragma unroll
        for (int r = 0; r < 4; ++r) {
            const int m  = r * 32 + m_st;
            const int lc = c_st ^ (m & 7);
            gll16(Abase + (size_t)m * 512 + k0 + lc * 8,
                  (char*)As + r * 4096 + wave * 1024);
        }
#pragma unroll
        for (int r = 0; r < 4; ++r) {
            const int m  = r * 32 + m_st;
            const int lc = c_st ^ (m & 7);
            gll16(Bbase + (size_t)m * 512 + k0 + lc * 8,
                  (char*)Bs + r * 4096 + wave * 1024);
        }
        __syncthreads();

#pragma unroll
        for (int kk = 0; kk < 2; ++kk) {
            half8 af[4], bf[4];
#pragma unroll
            for (int mi = 0; mi < 4; ++mi) {
                const int ra = wr * 64 + mi * 16 + (lane & 15);
                const int j  = kk * 4 + (lane >> 4);
                af[mi] = *(const half8*)((const char*)As +
                           ra * 128 + ((j ^ (ra & 7)) << 4));
            }
#pragma unroll
            for (int ni = 0; ni < 4; ++ni) {
                const int rb = wc * 64 + ni * 16 + (lane & 15);
                const int j  = kk * 4 + (lane >> 4);
                bf[ni] = *(const half8*)((const char*)Bs +
                           rb * 128 + ((j ^ (rb & 7)) << 4));
            }
#pragma unroll
            for (int mi = 0; mi < 4; ++mi)
#pragma unroll
                for (int ni = 0; ni < 4; ++ni)
                    acc[mi][ni] = __builtin_amdgcn_mfma_f32_16x16x32_f16(
                        af[mi], bf[ni], acc[mi][ni], 0, 0, 0);
        }
        __syncthreads();
    }

    const int row0 = bm * 128 + wr * 64;
    const int col0 = bn * 128 + wc * 64;
#pragma unroll
    for (int ni = 0; ni < 4; ++ni) {
        const int col = col0 + ni * 16 + (lane & 15);
        const float bv = bias[col];
#pragma unroll
        for (int mi = 0; mi < 4; ++mi) {
#pragma unroll
            for (int rg = 0; rg < 4; ++rg) {
                const int row = row0 + mi * 16 + (lane >> 4) * 4 + rg;
                C[(size_t)row * 640 + col] = (_Float16)(acc[mi][ni][rg] + bv);
            }
        }
    }
}

// ---------------------------------------------------------------------------
// Kernel 2: rowops — 1024 blocks x 256 threads (4 waves), 8 rows/wave in two
// 4-row ILP batches: all loads issued up front, butterflies batched per level
// (12 independent bpermutes/level). No lmax reduce (softmax without max-sub:
// logits are O(+-6), exact to ~1e-7 in f32).
// ---------------------------------------------------------------------------
__global__ __launch_bounds__(256, 4)
void rowops(const _Float16* __restrict__ logits, const float* __restrict__ gum,
            const float* __restrict__ cv, float* __restrict__ out,
            float* __restrict__ marginal) {
    __shared__ float smarg[640];
    const int t = threadIdx.x;
    const int wave = t >> 6, lane = t & 63;
    for (int i = t; i < 640; i += 256) smarg[i] = 0.f;
    __syncthreads();

    float mreg[2][5];
#pragma unroll
    for (int g = 0; g < 2; ++g)
#pragma unroll
        for (int j = 0; j < 5; ++j) mreg[g][j] = 0.f;

    const int r0 = blockIdx.x * 32 + wave * 8;

#pragma unroll
    for (int half = 0; half < 2; ++half) {
        const int rb = r0 + half * 4;
        // --- Phase A: all 40 loads for 4 rows, issued together ---
        float lv[4][5], gv[4][5];
#pragma unroll
        for (int rr = 0; rr < 4; ++rr) {
            const _Float16* lrow = logits + (size_t)(rb + rr) * V_CODES;
            const float*    grow = gum    + (size_t)(rb + rr) * V_CODES;
#pragma unroll
            for (int j = 0; j < 5; ++j) {
                lv[rr][j] = (float)lrow[lane + 64 * j];
                gv[rr][j] = grow[lane + 64 * j];
            }
        }
        // --- Phase B: per-lane partials ---
        float bestv[4], sum[4], ex[4][5];
        int besti[4];
#pragma unroll
        for (int rr = 0; rr < 4; ++rr) {
            bestv[rr] = -1e30f; besti[rr] = 0;
#pragma unroll
            for (int j = 0; j < 5; ++j) {
                const float nz = lv[rr][j] + gv[rr][j];
                if (nz > bestv[rr]) { bestv[rr] = nz; besti[rr] = lane + 64 * j; }
            }
            float s = 0.f;
#pragma unroll
            for (int j = 0; j < 5; ++j) { ex[rr][j] = __expf(lv[rr][j]); s += ex[rr][j]; }
            sum[rr] = s;
        }
        // --- Phase C: level-batched butterflies (argmax + sum) ---
#pragma unroll
        for (int off = 32; off; off >>= 1) {
#pragma unroll
            for (int rr = 0; rr < 4; ++rr) {
                const float ov = __shfl_down(bestv[rr], off);
                const int   oi = __shfl_down(besti[rr], off);
                const float os = __shfl_down(sum[rr], off);
                if (ov > bestv[rr] || (ov == bestv[rr] && oi < besti[rr])) {
                    bestv[rr] = ov; besti[rr] = oi;
                }
                sum[rr] += os;
            }
        }
#pragma unroll
        for (int rr = 0; rr < 4; ++rr) {
            besti[rr] = __shfl(besti[rr], 0);
            sum[rr]   = __shfl(sum[rr], 0);
        }
        // --- Phase D: marginal accumulate + codevector gather/out ---
#pragma unroll
        for (int rr = 0; rr < 4; ++rr) {
            const int r = rb + rr;
            const float inv = 1.f / sum[rr];
#pragma unroll
            for (int j = 0; j < 5; ++j) mreg[rr & 1][j] += ex[rr][j] * inv;
            const size_t n = (size_t)(r >> 1);
            const float2 cvv = ((const float2*)(cv +
                ((size_t)(rr & 1) * V_CODES + besti[rr]) * CV_DIM))[lane];
            ((float2*)(out + n * 256 + (size_t)(rr & 1) * CV_DIM))[lane] = cvv;
        }
    }

#pragma unroll
    for (int g = 0; g < 2; ++g)
#pragma unroll
        for (int j = 0; j < 5; ++j)
            atomicAdd(&smarg[g * V_CODES + lane + 64 * j], mreg[g][j]);
    __syncthreads();
    for (int i = t; i < 640; i += 256) atomicAdd(marginal + i, smarg[i]);
}

// ---------------------------------------------------------------------------
// Kernel 3: finalize perplexity from the global marginal (640 floats).
// ---------------------------------------------------------------------------
__global__ __launch_bounds__(640)
void finalize(const float* __restrict__ marginal, float* __restrict__ perp_out) {
    __shared__ float terms[640];
    __shared__ float gsum[2];
    const int t = threadIdx.x;

    const float m = marginal[t] * (1.0f / (float)M_ROWS);
    terms[t] = -m * __logf(m + 1e-7f);
    __syncthreads();

    if (t < 128) {
        const int g = t >> 6, lane = t & 63;
        float e = 0.f;
#pragma unroll
        for (int j = 0; j < 5; ++j) e += terms[g * V_CODES + lane + 64 * j];
#pragma unroll
        for (int off = 32; off; off >>= 1) e += __shfl_down(e, off);
        if (lane == 0) gsum[g] = e;
    }
    __syncthreads();
    if (t == 0) perp_out[0] = __expf(gsum[0]) + __expf(gsum[1]);
}

// ---------------------------------------------------------------------------
extern "C" void kernel_launch(void* const* d_in, const int* in_sizes, int n_in,
                              void* d_out, int out_size, void* d_ws, size_t ws_size,
                              hipStream_t stream) {
    (void)in_sizes; (void)n_in; (void)out_size; (void)ws_size;
    const float* hs = (const float*)d_in[0];   // (8,2048,512) f32
    const float* W  = (const float*)d_in[1];   // (512,640)    f32
    const float* bi = (const float*)d_in[2];   // (640,)       f32
    const float* cv = (const float*)d_in[3];   // (1,640,128)  f32
    const float* gu = (const float*)d_in[4];   // (32768,320)  f32
    float* out = (float*)d_out;                // 16384*256 + 1

    // ws: logits f16 (21 MB) + Af f16 (16.8 MB) + Wt f16 (0.64 MB) + marginal
    _Float16* logitsH = (_Float16*)d_ws;
    _Float16* Af      = logitsH + (size_t)M_ROWS * N_COLS;
    _Float16* Wt      = Af + (size_t)M_ROWS * K_DIM;
    float*    marginal= (float*)(Wt + (size_t)N_COLS * K_DIM);

    prep<<<2369, 256, 0, stream>>>(hs, W, Af, Wt, marginal);
    gemm<<<dim3(5, 128), 256, 0, stream>>>(Af, Wt, bi, logitsH);
    rowops<<<1024, 256, 0, stream>>>(logitsH, gu, cv, out, marginal);
    finalize<<<1, 640, 0, stream>>>(marginal, out + (size_t)M_ROWS * 256);
}

// Round 7
// 54.063 us; speedup vs baseline: 1.7066x; 1.4944x over previous
//
#include <hip/hip_runtime.h>

// Problem constants: B=8, S=2048, D=512, G=2, V=320, CV=128
#define M_ROWS 16384   // B*S
#define K_DIM  512
#define N_COLS 640     // G*V
#define V_CODES 320
#define CV_DIM 128

typedef _Float16 half8 __attribute__((ext_vector_type(8)));
typedef _Float16 half4v __attribute__((ext_vector_type(4)));
typedef float floatx4 __attribute__((ext_vector_type(4)));

__device__ inline void gll16(const void* g, void* l) {
    __builtin_amdgcn_global_load_lds(
        (const __attribute__((address_space(1))) void*)g,
        (__attribute__((address_space(3))) void*)l, 16, 0, 0);
}

// ---------------------------------------------------------------------------
// Kernel 0: prepW — LDS-tiled transpose W (512,640) f32 -> Wt (640,512) f16;
// block 320 zeroes the global marginal.
// ---------------------------------------------------------------------------
__global__ __launch_bounds__(256)
void prepW(const float* __restrict__ W, _Float16* __restrict__ Wt,
           float* __restrict__ marginal) {
    __shared__ float tile[32][33];
    const int b = blockIdx.x, t = threadIdx.x;
    if (b == 320) {
        for (int i = t; i < 640; i += 256) marginal[i] = 0.f;
        return;
    }
    const int n0 = (b % 20) * 32, k0 = (b / 20) * 32;
    {
        const int kk = t >> 3, nn4 = (t & 7) << 2;
        const float4 w = *(const float4*)(W + (size_t)(k0 + kk) * 640 + n0 + nn4);
        tile[kk][nn4 + 0] = w.x; tile[kk][nn4 + 1] = w.y;
        tile[kk][nn4 + 2] = w.z; tile[kk][nn4 + 3] = w.w;
    }
    __syncthreads();
    {
        const int nn = t >> 3, kk4 = (t & 7) << 2;
        half4v h = {(_Float16)tile[kk4 + 0][nn], (_Float16)tile[kk4 + 1][nn],
                    (_Float16)tile[kk4 + 2][nn], (_Float16)tile[kk4 + 3][nn]};
        *(half4v*)(Wt + (size_t)(n0 + nn) * 512 + k0 + kk4) = h;
    }
}

// ---------------------------------------------------------------------------
// Fused kernel: per block, 64 tokens x full 640 logits via MFMA (BK=32,
// double-buffered LDS staging), then in-register epilogue:
// wave w = (m-tile mi = w>>1, group g = w&1) holds 16 full 320-wide rows in
// acc; argmax(L+gumbel) + noise-free softmax via 4-level shfl_xor over
// 16-lane groups; codevector gather + out write; marginal via LDS+global
// atomics. No logits in HBM, no f16 logit rounding, no prep-A.
// ---------------------------------------------------------------------------
__global__ __launch_bounds__(512, 2)
void fused(const float* __restrict__ A, const _Float16* __restrict__ Bt,
           const float* __restrict__ bias, const float* __restrict__ gum,
           const float* __restrict__ cv, float* __restrict__ out,
           float* __restrict__ marginal) {
    __shared__ _Float16 As[2][64 * 32];    // 2 x 4 KB
    __shared__ _Float16 Bs[2][640 * 32];   // 2 x 40 KB
    __shared__ float smarg[640];
    const int t = threadIdx.x;
    const int wave = t >> 6, lane = t & 63;
    const int bm = blockIdx.x;
    const int mi = wave >> 1, g = wave & 1;
    const int c = lane & 15, kq = lane >> 4;

    // FIX (round 6 bug): 512 threads must zero all 640 entries — the old
    // `if (t < 640)` left smarg[512..639] as poisoned LDS -> NaN perplexity.
    for (int i = t; i < 640; i += 512) smarg[i] = 0.f;

    floatx4 acc[20];
#pragma unroll
    for (int nt = 0; nt < 20; ++nt) acc[nt] = (floatx4){0.f, 0.f, 0.f, 0.f};

    // A staging map: thread -> (row am, 8B half-chunk ad); swizzle chunk^(row&3)
    const int am = t >> 3, ad = t & 7;
    const int a_wr = am * 64 + (((ad >> 1) ^ (am & 3)) << 4) + (ad & 1) * 8;
    const float* Aptr = A + (size_t)(bm * 64 + am) * 512 + ad * 4;

    auto STAGE = [&](int buf, int k0) {
        const float4 av = *(const float4*)(Aptr + k0);   // issue first (vmcnt-counted)
#pragma unroll
        for (int s = 0; s < 5; ++s) {
            const int qq = t + 512 * s;                  // 0..2559
            const int n  = qq >> 2, j = qq & 3;
            gll16(Bt + (size_t)n * 512 + k0 + ((j ^ (n & 3)) << 3),
                  (char*)(&Bs[buf][0]) + qq * 16);
        }
        const half4v h = {(_Float16)av.x, (_Float16)av.y,
                          (_Float16)av.z, (_Float16)av.w};
        *(half4v*)((char*)(&As[buf][0]) + a_wr) = h;
    };

    STAGE(0, 0);
    __syncthreads();

    for (int kt = 0; kt < 16; ++kt) {
        const int cur = kt & 1;
        if (kt < 15) STAGE(cur ^ 1, (kt + 1) * 32);
        const int ra = mi * 16 + c;
        const half8 af = *(const half8*)((const char*)(&As[cur][0]) +
                          ra * 64 + ((kq ^ (ra & 3)) << 4));
#pragma unroll
        for (int nt = 0; nt < 20; ++nt) {
            const int rb = g * 320 + nt * 16 + c;
            const half8 bf = *(const half8*)((const char*)(&Bs[cur][0]) +
                              rb * 64 + ((kq ^ (rb & 3)) << 4));
            acc[nt] = __builtin_amdgcn_mfma_f32_16x16x32_f16(af, bf, acc[nt], 0, 0, 0);
        }
        __syncthreads();
    }

    // ---- epilogue ----
    float bcol[20];
#pragma unroll
    for (int nt = 0; nt < 20; ++nt) bcol[nt] = bias[g * 320 + nt * 16 + c];

    float mcontrib[20];
#pragma unroll
    for (int nt = 0; nt < 20; ++nt) mcontrib[nt] = 0.f;

#pragma unroll
    for (int rg = 0; rg < 4; ++rg) {
        const int ntok = bm * 64 + mi * 16 + kq * 4 + rg;   // token row (per-lane)
        // logits (f32) for this row, this lane's 20 cols
        float lg[20];
#pragma unroll
        for (int nt = 0; nt < 20; ++nt) lg[nt] = acc[nt][rg] + bcol[nt];
        // gumbels
        const float* gr = gum + ((size_t)ntok * 2 + g) * V_CODES + c;
        float gv[20];
#pragma unroll
        for (int nt = 0; nt < 20; ++nt) gv[nt] = gr[nt * 16];
        // per-lane argmax of noisy logits (global col index, lowest-idx tie)
        float best = -1e30f; int bidx = 0;
#pragma unroll
        for (int nt = 0; nt < 20; ++nt) {
            const float nz = lg[nt] + gv[nt];
            const int v = nt * 16 + c;
            if (nz > best) { best = nz; bidx = v; }
        }
        // 16-lane all-reduce argmax (xor 1,2,4,8 stays in quarter-wave)
#pragma unroll
        for (int mask = 1; mask <= 8; mask <<= 1) {
            const float ob = __shfl_xor(best, mask);
            const int   oi = __shfl_xor(bidx, mask);
            if (ob > best || (ob == best && oi < bidx)) { best = ob; bidx = oi; }
        }
        // noise-free softmax (no max-sub: logits are O(+-6), f32-exact enough)
        float s = 0.f;
#pragma unroll
        for (int nt = 0; nt < 20; ++nt) { lg[nt] = __expf(lg[nt]); s += lg[nt]; }
#pragma unroll
        for (int mask = 1; mask <= 8; mask <<= 1) s += __shfl_xor(s, mask);
        const float inv = 1.f / s;
#pragma unroll
        for (int nt = 0; nt < 20; ++nt) mcontrib[nt] += lg[nt] * inv;
        // codevector gather + straight-through output (one-hot row bidx)
        const float4* cvp = (const float4*)(cv + ((size_t)g * V_CODES + bidx) * CV_DIM)
                            + c * 2;
        const float4 v0 = cvp[0], v1 = cvp[1];
        float4* op = (float4*)(out + (size_t)ntok * 256 + g * CV_DIM) + c * 2;
        op[0] = v0; op[1] = v1;
    }

    // marginal: reduce the 4 quarter-wave groups (same cols), then LDS atomics
#pragma unroll
    for (int nt = 0; nt < 20; ++nt) {
        mcontrib[nt] += __shfl_xor(mcontrib[nt], 16);
        mcontrib[nt] += __shfl_xor(mcontrib[nt], 32);
    }
    if (lane < 16) {
#pragma unroll
        for (int nt = 0; nt < 20; ++nt)
            atomicAdd(&smarg[g * V_CODES + nt * 16 + c], mcontrib[nt]);
    }
    __syncthreads();
    for (int i = t; i < 640; i += 512) atomicAdd(marginal + i, smarg[i]);
}

// ---------------------------------------------------------------------------
// Kernel 2: finalize perplexity from the global marginal (640 floats).
// ---------------------------------------------------------------------------
__global__ __launch_bounds__(640)
void finalize(const float* __restrict__ marginal, float* __restrict__ perp_out) {
    __shared__ float terms[640];
    __shared__ float gsum[2];
    const int t = threadIdx.x;

    const float m = marginal[t] * (1.0f / (float)M_ROWS);
    terms[t] = -m * __logf(m + 1e-7f);
    __syncthreads();

    if (t < 128) {
        const int g = t >> 6, lane = t & 63;
        float e = 0.f;
#pragma unroll
        for (int j = 0; j < 5; ++j) e += terms[g * V_CODES + lane + 64 * j];
#pragma unroll
        for (int off = 32; off; off >>= 1) e += __shfl_down(e, off);
        if (lane == 0) gsum[g] = e;
    }
    __syncthreads();
    if (t == 0) perp_out[0] = __expf(gsum[0]) + __expf(gsum[1]);
}

// ---------------------------------------------------------------------------
extern "C" void kernel_launch(void* const* d_in, const int* in_sizes, int n_in,
                              void* d_out, int out_size, void* d_ws, size_t ws_size,
                              hipStream_t stream) {
    (void)in_sizes; (void)n_in; (void)out_size; (void)ws_size;
    const float* hs = (const float*)d_in[0];   // (8,2048,512) f32
    const float* W  = (const float*)d_in[1];   // (512,640)    f32
    const float* bi = (const float*)d_in[2];   // (640,)       f32
    const float* cv = (const float*)d_in[3];   // (1,640,128)  f32
    const float* gu = (const float*)d_in[4];   // (32768,320)  f32
    float* out = (float*)d_out;                // 16384*256 + 1

    // ws: Wt f16 (640 KB) + marginal (640 f32)
    _Float16* Wt       = (_Float16*)d_ws;
    float*    marginal = (float*)(Wt + (size_t)N_COLS * K_DIM);

    prepW<<<321, 256, 0, stream>>>(W, Wt, marginal);
    fused<<<256, 512, 0, stream>>>(hs, Wt, bi, gu, cv, out, marginal);
    finalize<<<1, 640, 0, stream>>>(marginal, out + (size_t)M_ROWS * 256);
}

// Round 8
// 49.008 us; speedup vs baseline: 1.8826x; 1.1032x over previous
//
#include <hip/hip_runtime.h>

// Problem constants: B=8, S=2048, D=512, G=2, V=320, CV=128
#define M_ROWS 16384   // B*S
#define K_DIM  512
#define N_COLS 640     // G*V
#define V_CODES 320
#define CV_DIM 128

typedef _Float16 half8 __attribute__((ext_vector_type(8)));
typedef _Float16 half4v __attribute__((ext_vector_type(4)));
typedef float floatx4 __attribute__((ext_vector_type(4)));

__device__ inline void gll16(const void* g, void* l) {
    __builtin_amdgcn_global_load_lds(
        (const __attribute__((address_space(1))) void*)g,
        (__attribute__((address_space(3))) void*)l, 16, 0, 0);
}

// ---------------------------------------------------------------------------
// Kernel 0: prepW — LDS-tiled transpose W (512,640) f32 -> Wt (640,512) f16;
// block 320 zeroes the global marginal.
// ---------------------------------------------------------------------------
__global__ __launch_bounds__(256)
void prepW(const float* __restrict__ W, _Float16* __restrict__ Wt,
           float* __restrict__ marginal) {
    __shared__ float tile[32][33];
    const int b = blockIdx.x, t = threadIdx.x;
    if (b == 320) {
        for (int i = t; i < 640; i += 256) marginal[i] = 0.f;
        return;
    }
    const int n0 = (b % 20) * 32, k0 = (b / 20) * 32;
    {
        const int kk = t >> 3, nn4 = (t & 7) << 2;
        const float4 w = *(const float4*)(W + (size_t)(k0 + kk) * 640 + n0 + nn4);
        tile[kk][nn4 + 0] = w.x; tile[kk][nn4 + 1] = w.y;
        tile[kk][nn4 + 2] = w.z; tile[kk][nn4 + 3] = w.w;
    }
    __syncthreads();
    {
        const int nn = t >> 3, kk4 = (t & 7) << 2;
        half4v h = {(_Float16)tile[kk4 + 0][nn], (_Float16)tile[kk4 + 1][nn],
                    (_Float16)tile[kk4 + 2][nn], (_Float16)tile[kk4 + 3][nn]};
        *(half4v*)(Wt + (size_t)(n0 + nn) * 512 + k0 + kk4) = h;
    }
}

// ---------------------------------------------------------------------------
// Fused kernel, group-split: grid (256 bm, 2 g), 256 threads = 4 waves.
// Per block: 64 tokens x one group's 320 logits via MFMA (BK=32, dbuf LDS),
// wave mi owns rows [mi*16, mi*16+16) x all 320 cols in acc[20].
// LDS ~49.5 KB -> 2 independent blocks/CU (separate barrier domains), so one
// block's staging drain overlaps the other's MFMA/epilogue.
// ---------------------------------------------------------------------------
__global__ __launch_bounds__(256, 2)
void fused(const float* __restrict__ A, const _Float16* __restrict__ Bt,
           const float* __restrict__ bias, const float* __restrict__ gum,
           const float* __restrict__ cv, float* __restrict__ out,
           float* __restrict__ marginal) {
    __shared__ _Float16 As[2][64 * 32];    // 2 x 4 KB
    __shared__ _Float16 Bs[2][320 * 32];   // 2 x 20 KB
    __shared__ float smarg[320];
    const int t = threadIdx.x;
    const int wave = t >> 6, lane = t & 63;
    const int bm = blockIdx.x, g = blockIdx.y;
    const int mi = wave;
    const int c = lane & 15, kq = lane >> 4;

    for (int i = t; i < 320; i += 256) smarg[i] = 0.f;

    floatx4 acc[20];
#pragma unroll
    for (int nt = 0; nt < 20; ++nt) acc[nt] = (floatx4){0.f, 0.f, 0.f, 0.f};

    // A staging: thread t -> (row am = t>>2, 16B chunk ad = t&3), swizzle ^(am&3)
    const int am = t >> 2, ad = t & 3;
    const int a_wr = am * 64 + ((ad ^ (am & 3)) << 4);
    const float* Aptr = A + (size_t)(bm * 64 + am) * 512 + ad * 8;

    const _Float16* Bg = Bt + (size_t)g * V_CODES * K_DIM;

    auto STAGE = [&](int buf, int k0) {
        const float4 av0 = *(const float4*)(Aptr + k0);
        const float4 av1 = *(const float4*)(Aptr + k0 + 4);
#pragma unroll
        for (int s = 0; s < 5; ++s) {
            const int q = t + 256 * s;               // 0..1279
            const int n = q >> 2, j = q & 3;         // row 0..319, chunk 0..3
            gll16(Bg + (size_t)n * 512 + k0 + ((j ^ (n & 3)) << 3),
                  (char*)(&Bs[buf][0]) + q * 16);
        }
        const half8 h = {(_Float16)av0.x, (_Float16)av0.y, (_Float16)av0.z,
                         (_Float16)av0.w, (_Float16)av1.x, (_Float16)av1.y,
                         (_Float16)av1.z, (_Float16)av1.w};
        *(half8*)((char*)(&As[buf][0]) + a_wr) = h;
    };

    STAGE(0, 0);
    __syncthreads();

    for (int kt = 0; kt < 16; ++kt) {
        const int cur = kt & 1;
        if (kt < 15) STAGE(cur ^ 1, (kt + 1) * 32);
        const int ra = mi * 16 + c;
        const half8 af = *(const half8*)((const char*)(&As[cur][0]) +
                          ra * 64 + ((kq ^ (ra & 3)) << 4));
#pragma unroll
        for (int nt = 0; nt < 20; ++nt) {
            const int rb = nt * 16 + c;
            const half8 bf = *(const half8*)((const char*)(&Bs[cur][0]) +
                              rb * 64 + ((kq ^ (rb & 3)) << 4));
            acc[nt] = __builtin_amdgcn_mfma_f32_16x16x32_f16(af, bf, acc[nt], 0, 0, 0);
        }
        __syncthreads();
    }

    // ---- epilogue (wave mi: 16 rows x group g's 320 cols, all in regs) ----
    float bcol[20];
#pragma unroll
    for (int nt = 0; nt < 20; ++nt) bcol[nt] = bias[g * V_CODES + nt * 16 + c];

    float mcontrib[20];
#pragma unroll
    for (int nt = 0; nt < 20; ++nt) mcontrib[nt] = 0.f;

#pragma unroll
    for (int rg = 0; rg < 4; ++rg) {
        const int ntok = bm * 64 + mi * 16 + kq * 4 + rg;   // token (per-lane)
        float lg[20];
#pragma unroll
        for (int nt = 0; nt < 20; ++nt) lg[nt] = acc[nt][rg] + bcol[nt];
        const float* gr = gum + ((size_t)ntok * 2 + g) * V_CODES + c;
        float gv[20];
#pragma unroll
        for (int nt = 0; nt < 20; ++nt) gv[nt] = gr[nt * 16];
        // per-lane argmax over this lane's 20 cols (lowest-index tie)
        float best = -1e30f; int bidx = 0;
#pragma unroll
        for (int nt = 0; nt < 20; ++nt) {
            const float nz = lg[nt] + gv[nt];
            const int v = nt * 16 + c;
            if (nz > best) { best = nz; bidx = v; }
        }
        // 16-lane all-reduce argmax (xor 1..8 stays within quarter-wave)
#pragma unroll
        for (int mask = 1; mask <= 8; mask <<= 1) {
            const float ob = __shfl_xor(best, mask);
            const int   oi = __shfl_xor(bidx, mask);
            if (ob > best || (ob == best && oi < bidx)) { best = ob; bidx = oi; }
        }
        // noise-free softmax (no max-sub: logits O(+-6), f32-exact enough)
        float s = 0.f;
#pragma unroll
        for (int nt = 0; nt < 20; ++nt) { lg[nt] = __expf(lg[nt]); s += lg[nt]; }
#pragma unroll
        for (int mask = 1; mask <= 8; mask <<= 1) s += __shfl_xor(s, mask);
        const float inv = 1.f / s;
#pragma unroll
        for (int nt = 0; nt < 20; ++nt) mcontrib[nt] += lg[nt] * inv;
        // codevector gather + straight-through output (one-hot row bidx)
        const float4* cvp = (const float4*)(cv + ((size_t)g * V_CODES + bidx) * CV_DIM)
                            + c * 2;
        const float4 v0 = cvp[0], v1 = cvp[1];
        float4* op = (float4*)(out + (size_t)ntok * 256 + g * CV_DIM) + c * 2;
        op[0] = v0; op[1] = v1;
    }

    // marginal: reduce 4 quarter-wave groups (same cols), LDS + global atomics
#pragma unroll
    for (int nt = 0; nt < 20; ++nt) {
        mcontrib[nt] += __shfl_xor(mcontrib[nt], 16);
        mcontrib[nt] += __shfl_xor(mcontrib[nt], 32);
    }
    if (lane < 16) {
#pragma unroll
        for (int nt = 0; nt < 20; ++nt)
            atomicAdd(&smarg[nt * 16 + c], mcontrib[nt]);
    }
    __syncthreads();
    for (int i = t; i < 320; i += 256)
        atomicAdd(marginal + g * V_CODES + i, smarg[i]);
}

// ---------------------------------------------------------------------------
// Kernel 2: finalize perplexity from the global marginal (640 floats).
// ---------------------------------------------------------------------------
__global__ __launch_bounds__(640)
void finalize(const float* __restrict__ marginal, float* __restrict__ perp_out) {
    __shared__ float terms[640];
    __shared__ float gsum[2];
    const int t = threadIdx.x;

    const float m = marginal[t] * (1.0f / (float)M_ROWS);
    terms[t] = -m * __logf(m + 1e-7f);
    __syncthreads();

    if (t < 128) {
        const int g = t >> 6, lane = t & 63;
        float e = 0.f;
#pragma unroll
        for (int j = 0; j < 5; ++j) e += terms[g * V_CODES + lane + 64 * j];
#pragma unroll
        for (int off = 32; off; off >>= 1) e += __shfl_down(e, off);
        if (lane == 0) gsum[g] = e;
    }
    __syncthreads();
    if (t == 0) perp_out[0] = __expf(gsum[0]) + __expf(gsum[1]);
}

// ---------------------------------------------------------------------------
extern "C" void kernel_launch(void* const* d_in, const int* in_sizes, int n_in,
                              void* d_out, int out_size, void* d_ws, size_t ws_size,
                              hipStream_t stream) {
    (void)in_sizes; (void)n_in; (void)out_size; (void)ws_size;
    const float* hs = (const float*)d_in[0];   // (8,2048,512) f32
    const float* W  = (const float*)d_in[1];   // (512,640)    f32
    const float* bi = (const float*)d_in[2];   // (640,)       f32
    const float* cv = (const float*)d_in[3];   // (1,640,128)  f32
    const float* gu = (const float*)d_in[4];   // (32768,320)  f32
    float* out = (float*)d_out;                // 16384*256 + 1

    // ws: Wt f16 (640 KB) + marginal (640 f32)
    _Float16* Wt       = (_Float16*)d_ws;
    float*    marginal = (float*)(Wt + (size_t)N_COLS * K_DIM);

    prepW<<<321, 256, 0, stream>>>(W, Wt, marginal);
    fused<<<dim3(256, 2), 256, 0, stream>>>(hs, Wt, bi, gu, cv, out, marginal);
    finalize<<<1, 640, 0, stream>>>(marginal, out + (size_t)M_ROWS * 256);
}